// Round 1
// baseline (331.658 us; speedup 1.0000x reference)
//
#include <hip/hip_runtime.h>

// DropBlock, N=64 C=64 H=80 W=80, block_size=5 (top/left-clipped window max).
#define DB_H 80
#define DB_W 80
#define DB_PLANE (DB_H * DB_W)               // 6400
#define DB_NPLANES 4096                      // N*C
#define DB_WORDS_PER_PLANE (DB_PLANE / 32)   // 200
#define DB_TOTAL (DB_PLANE * DB_NPLANES)     // 26214400
#define DB_TOTAL_WORDS (DB_TOTAL / 32)       // 819200
#define DB_COUNT_F 26214400.0f               // 25 * 2^20 — exact in f32

// Kernel 1: per-plane separable 5x5 window-OR, zero count, optional bit-pack.
__global__ __launch_bounds__(256) void db_mask_kernel(
    const int* __restrict__ mask,
    unsigned int* __restrict__ bits,
    unsigned int* __restrict__ count_zeros,
    int store_bits)
{
    __shared__ unsigned char sm[DB_PLANE];  // seed mask (0/1 bytes)
    __shared__ unsigned char sr[DB_PLANE];  // row-OR result
    const int plane = blockIdx.x;
    const int t = threadIdx.x;
    const int* mp = mask + (size_t)plane * DB_PLANE;

    // Load 6400 int32 (0/1) as 1600 int4, pack 4 bytes per LDS dword store.
    for (int idx = t; idx < DB_PLANE / 4; idx += 256) {
        int4 v = ((const int4*)mp)[idx];
        ((unsigned int*)sm)[idx] =
            (unsigned int)(v.x & 1) | ((unsigned int)(v.y & 1) << 8) |
            ((unsigned int)(v.z & 1) << 16) | ((unsigned int)(v.w & 1) << 24);
    }
    __syncthreads();

    // Row pass: sr[i][j] = OR_{dw=0..4, j-dw>=0} sm[i][j-dw]
    for (int e = t; e < DB_PLANE; e += 256) {
        int i = e / DB_W, j = e - i * DB_W;
        unsigned int v = sm[e];
        int lo = (j >= 4) ? (j - 4) : 0;
        for (int jj = lo; jj < j; ++jj) v |= sm[i * DB_W + jj];
        sr[e] = (unsigned char)v;
    }
    __syncthreads();

    // Col pass + count zeros + pack bits (bit set = blocked).
    unsigned int zeros = 0;
    for (int w = t; w < DB_WORDS_PER_PLANE; w += 256) {
        unsigned int bw = 0;
        for (int b = 0; b < 32; ++b) {
            int e = w * 32 + b;
            int i = e / DB_W, j = e - i * DB_W;
            unsigned int v = sr[e];
            int lo = (i >= 4) ? (i - 4) : 0;
            for (int ii = lo; ii < i; ++ii) v |= sr[ii * DB_W + j];
            bw |= (v & 1u) << b;
        }
        zeros += 32u - (unsigned int)__popc(bw);
        if (store_bits) bits[(size_t)plane * DB_WORDS_PER_PLANE + w] = bw;
    }

    // Wave-64 reduce, one atomic per wave. Integer -> exact & deterministic.
    for (int off = 32; off > 0; off >>= 1)
        zeros += (unsigned int)__shfl_down((int)zeros, off, 64);
    if ((t & 63) == 0)
        atomicAdd(count_zeros, zeros);
}

// Kernel 2 (fast path): out = bit ? 0 : x * (countM / count_zeros), float4.
__global__ __launch_bounds__(256) void db_apply_bits(
    const float* __restrict__ x,
    const unsigned int* __restrict__ bits,
    const unsigned int* __restrict__ count_zeros,
    float* __restrict__ out)
{
    const float scale = DB_COUNT_F / (float)(*count_zeros);
    const size_t NG = DB_TOTAL / 4;
    const size_t stride = (size_t)gridDim.x * blockDim.x;
    for (size_t g = (size_t)blockIdx.x * blockDim.x + threadIdx.x; g < NG; g += stride) {
        float4 v = ((const float4*)x)[g];
        unsigned int wb = bits[g >> 3];
        unsigned int sh = ((unsigned int)g & 7u) * 4u;
        float4 o;
        o.x = ((wb >> (sh + 0)) & 1u) ? 0.0f : v.x * scale;
        o.y = ((wb >> (sh + 1)) & 1u) ? 0.0f : v.y * scale;
        o.z = ((wb >> (sh + 2)) & 1u) ? 0.0f : v.z * scale;
        o.w = ((wb >> (sh + 3)) & 1u) ? 0.0f : v.w * scale;
        ((float4*)out)[g] = o;
    }
}

// Kernel 2 (fallback if ws too small for bits): recompute block mask per plane.
__global__ __launch_bounds__(256) void db_apply_recompute(
    const float* __restrict__ x,
    const int* __restrict__ mask,
    const unsigned int* __restrict__ count_zeros,
    float* __restrict__ out)
{
    __shared__ unsigned char sm[DB_PLANE];
    __shared__ unsigned char sr[DB_PLANE];
    const float scale = DB_COUNT_F / (float)(*count_zeros);
    const int plane = blockIdx.x;
    const int t = threadIdx.x;
    const int* mp = mask + (size_t)plane * DB_PLANE;

    for (int idx = t; idx < DB_PLANE / 4; idx += 256) {
        int4 v = ((const int4*)mp)[idx];
        ((unsigned int*)sm)[idx] =
            (unsigned int)(v.x & 1) | ((unsigned int)(v.y & 1) << 8) |
            ((unsigned int)(v.z & 1) << 16) | ((unsigned int)(v.w & 1) << 24);
    }
    __syncthreads();
    for (int e = t; e < DB_PLANE; e += 256) {
        int i = e / DB_W, j = e - i * DB_W;
        unsigned int v = sm[e];
        int lo = (j >= 4) ? (j - 4) : 0;
        for (int jj = lo; jj < j; ++jj) v |= sm[i * DB_W + jj];
        sr[e] = (unsigned char)v;
    }
    __syncthreads();
    const float* xp = x + (size_t)plane * DB_PLANE;
    float* op = out + (size_t)plane * DB_PLANE;
    for (int e = t; e < DB_PLANE; e += 256) {
        int i = e / DB_W, j = e - i * DB_W;
        unsigned int v = sr[e];
        int lo = (i >= 4) ? (i - 4) : 0;
        for (int ii = lo; ii < i; ++ii) v |= sr[ii * DB_W + j];
        op[e] = (v & 1u) ? 0.0f : xp[e] * scale;
    }
}

extern "C" void kernel_launch(void* const* d_in, const int* in_sizes, int n_in,
                              void* d_out, int out_size, void* d_ws, size_t ws_size,
                              hipStream_t stream) {
    const float* x = (const float*)d_in[0];
    const int* mask = (const int*)d_in[1];
    float* out = (float*)d_out;

    unsigned int* counter = (unsigned int*)d_ws;
    unsigned int* bits = (unsigned int*)((char*)d_ws + 16);
    const size_t bits_bytes = (size_t)DB_TOTAL_WORDS * sizeof(unsigned int);
    const bool use_bits = ws_size >= 16 + bits_bytes;

    // Zero the counter every call (ws is poisoned once, never re-poisoned).
    hipMemsetAsync(d_ws, 0, 16, stream);

    db_mask_kernel<<<DB_NPLANES, 256, 0, stream>>>(mask, bits, counter,
                                                   use_bits ? 1 : 0);
    if (use_bits) {
        db_apply_bits<<<2048, 256, 0, stream>>>(x, bits, counter, out);
    } else {
        db_apply_recompute<<<DB_NPLANES, 256, 0, stream>>>(x, mask, counter, out);
    }
}

// Round 2
// 143.103 us; speedup vs baseline: 2.3176x; 2.3176x over previous
//
#include <hip/hip_runtime.h>

// DropBlock, N=64 C=64 H=80 W=80, block_size=5 (top/left-clipped window max).
// Bitboard formulation: seed mask packed 1 bit/elem via __ballot; width-5
// window-OR done with 128-bit shifts (row pass) + 5-row OR (col pass).
#define DB_H 80
#define DB_W 80
#define DB_PLANE (DB_H * DB_W)               // 6400
#define DB_NPLANES 4096                      // N*C
#define DB_ROW_WORDS 3                       // 96-bit padded row of block mask
#define DB_PLANE_WORDS (DB_H * DB_ROW_WORDS) // 240
#define DB_TOTAL (DB_PLANE * DB_NPLANES)     // 26214400
#define DB_COUNT_F 26214400.0f               // 25 * 2^20 — exact in f32
#define PPB 4                                // planes per block (1 per wave)

// Kernel 1: per-plane bitboard window-OR + zero count + packed mask store.
__global__ __launch_bounds__(256) void db_mask_kernel(
    const int* __restrict__ mask,
    unsigned int* __restrict__ bits,
    unsigned int* __restrict__ count_zeros)
{
    __shared__ unsigned long long P[PPB][104];          // packed seed bits
    __shared__ unsigned int RO[PPB][DB_PLANE_WORDS];    // row-OR, 3 words/row
    const int wid = threadIdx.x >> 6;
    const int lane = threadIdx.x & 63;
    const int plane = blockIdx.x * PPB + wid;
    const int* mp = mask + plane * DB_PLANE;
    unsigned long long* Pp = P[wid];
    unsigned int* ro = RO[wid];

    // Phase 1: pack seed mask 1 bit/elem via wave ballot (coalesced 256B/it).
    #pragma unroll 4
    for (int k = 0; k < 100; ++k) {
        unsigned long long bal = __ballot(mp[k * 64 + lane] & 1);
        if (lane == 0) Pp[k] = bal;
    }
    if (lane < 4) Pp[100 + lane] = 0ULL;
    __syncthreads();

    // Phase 2: row sliding-OR (width 5, left-clipped): r = OR_{s=0..4} m<<s
    // on the row's 80 bits held as 128-bit (b:a). Zero-fill at bit 0 = clip.
    for (int r = lane; r < DB_H; r += 64) {
        int bitpos = r * DB_W;
        int q = bitpos >> 6, off = bitpos & 63;
        unsigned long long a, b;
        if (off) {
            a = (Pp[q] >> off) | (Pp[q + 1] << (64 - off));
            b = (Pp[q + 1] >> off) | (Pp[q + 2] << (64 - off));
        } else {
            a = Pp[q]; b = Pp[q + 1];
        }
        b &= 0xFFFFULL;
        unsigned long long ra = a, rb = b;
        #pragma unroll
        for (int s = 1; s <= 4; ++s) {
            ra |= a << s;
            rb |= (b << s) | (a >> (64 - s));
        }
        rb &= 0xFFFFULL;
        ro[r * 3 + 0] = (unsigned int)ra;
        ro[r * 3 + 1] = (unsigned int)(ra >> 32);
        ro[r * 3 + 2] = (unsigned int)rb;
    }
    __syncthreads();

    // Phase 3: col OR over rows i-4..i (top clip), count zeros, store bits.
    unsigned int zeros = 0;
    for (int i = lane; i < DB_H; i += 64) {
        int lo = (i >= 4) ? i - 4 : 0;
        unsigned int c0 = 0, c1 = 0, c2 = 0;
        for (int ii = lo; ii <= i; ++ii) {
            c0 |= ro[ii * 3 + 0];
            c1 |= ro[ii * 3 + 1];
            c2 |= ro[ii * 3 + 2];
        }
        zeros += 80u - __popc(c0) - __popc(c1) - __popc(c2);
        unsigned int* bp = bits + plane * DB_PLANE_WORDS + i * 3;
        bp[0] = c0; bp[1] = c1; bp[2] = c2;
    }
    for (int off = 32; off > 0; off >>= 1)
        zeros += (unsigned int)__shfl_down((int)zeros, off, 64);
    if (lane == 0) atomicAdd(count_zeros, zeros);
}

// Kernel 2: out = blocked ? 0 : x * (countM / count_zeros), float4 stream.
__global__ __launch_bounds__(256) void db_apply_bits(
    const float4* __restrict__ x,
    const unsigned int* __restrict__ bits,
    const unsigned int* __restrict__ count_zeros,
    float4* __restrict__ out)
{
    const float scale = DB_COUNT_F / (float)(*count_zeros);
    const int NG = DB_TOTAL / 4;
    const int stride = gridDim.x * blockDim.x;
    for (int g = blockIdx.x * blockDim.x + threadIdx.x; g < NG; g += stride) {
        float4 v = x[g];
        int e = g * 4;
        int plane = e / DB_PLANE;
        int ep = e - plane * DB_PLANE;
        int i = ep / DB_W;
        int j = ep - i * DB_W;   // j % 4 == 0; 4 bits never cross a word
        unsigned int wb =
            bits[plane * DB_PLANE_WORDS + i * 3 + (j >> 5)] >> (j & 31);
        float4 o;
        o.x = (wb & 1u) ? 0.0f : v.x * scale;
        o.y = (wb & 2u) ? 0.0f : v.y * scale;
        o.z = (wb & 4u) ? 0.0f : v.z * scale;
        o.w = (wb & 8u) ? 0.0f : v.w * scale;
        out[g] = o;
    }
}

// Fallback (ws too small for bits): recompute block mask per plane, apply.
__global__ __launch_bounds__(256) void db_apply_recompute(
    const float* __restrict__ x,
    const int* __restrict__ mask,
    const unsigned int* __restrict__ count_zeros,
    float* __restrict__ out)
{
    __shared__ unsigned long long P[PPB][104];
    __shared__ unsigned int RO[PPB][DB_PLANE_WORDS];
    const float scale = DB_COUNT_F / (float)(*count_zeros);
    const int wid = threadIdx.x >> 6;
    const int lane = threadIdx.x & 63;
    const int plane = blockIdx.x * PPB + wid;
    const int* mp = mask + plane * DB_PLANE;
    unsigned long long* Pp = P[wid];
    unsigned int* ro = RO[wid];

    #pragma unroll 4
    for (int k = 0; k < 100; ++k) {
        unsigned long long bal = __ballot(mp[k * 64 + lane] & 1);
        if (lane == 0) Pp[k] = bal;
    }
    if (lane < 4) Pp[100 + lane] = 0ULL;
    __syncthreads();
    for (int r = lane; r < DB_H; r += 64) {
        int bitpos = r * DB_W;
        int q = bitpos >> 6, off = bitpos & 63;
        unsigned long long a, b;
        if (off) {
            a = (Pp[q] >> off) | (Pp[q + 1] << (64 - off));
            b = (Pp[q + 1] >> off) | (Pp[q + 2] << (64 - off));
        } else {
            a = Pp[q]; b = Pp[q + 1];
        }
        b &= 0xFFFFULL;
        unsigned long long ra = a, rb = b;
        #pragma unroll
        for (int s = 1; s <= 4; ++s) {
            ra |= a << s;
            rb |= (b << s) | (a >> (64 - s));
        }
        rb &= 0xFFFFULL;
        ro[r * 3 + 0] = (unsigned int)ra;
        ro[r * 3 + 1] = (unsigned int)(ra >> 32);
        ro[r * 3 + 2] = (unsigned int)rb;
    }
    __syncthreads();
    // Col OR into LDS block-mask, then stream-apply x for this plane.
    __shared__ unsigned int BM[PPB][DB_PLANE_WORDS];
    unsigned int* bm = BM[wid];
    for (int i = lane; i < DB_H; i += 64) {
        int lo = (i >= 4) ? i - 4 : 0;
        unsigned int c0 = 0, c1 = 0, c2 = 0;
        for (int ii = lo; ii <= i; ++ii) {
            c0 |= ro[ii * 3 + 0];
            c1 |= ro[ii * 3 + 1];
            c2 |= ro[ii * 3 + 2];
        }
        bm[i * 3 + 0] = c0; bm[i * 3 + 1] = c1; bm[i * 3 + 2] = c2;
    }
    __syncthreads();
    const float* xp = x + plane * DB_PLANE;
    float* op = out + plane * DB_PLANE;
    for (int e = lane; e < DB_PLANE; e += 64) {
        int i = e / DB_W, j = e - i * DB_W;
        unsigned int wb = bm[i * 3 + (j >> 5)] >> (j & 31);
        op[e] = (wb & 1u) ? 0.0f : xp[e] * scale;
    }
}

// Count-only kernel for the fallback path.
__global__ __launch_bounds__(256) void db_count_kernel(
    const int* __restrict__ mask,
    unsigned int* __restrict__ count_zeros)
{
    __shared__ unsigned long long P[PPB][104];
    __shared__ unsigned int RO[PPB][DB_PLANE_WORDS];
    const int wid = threadIdx.x >> 6;
    const int lane = threadIdx.x & 63;
    const int plane = blockIdx.x * PPB + wid;
    const int* mp = mask + plane * DB_PLANE;
    unsigned long long* Pp = P[wid];
    unsigned int* ro = RO[wid];
    #pragma unroll 4
    for (int k = 0; k < 100; ++k) {
        unsigned long long bal = __ballot(mp[k * 64 + lane] & 1);
        if (lane == 0) Pp[k] = bal;
    }
    if (lane < 4) Pp[100 + lane] = 0ULL;
    __syncthreads();
    for (int r = lane; r < DB_H; r += 64) {
        int bitpos = r * DB_W;
        int q = bitpos >> 6, off = bitpos & 63;
        unsigned long long a, b;
        if (off) {
            a = (Pp[q] >> off) | (Pp[q + 1] << (64 - off));
            b = (Pp[q + 1] >> off) | (Pp[q + 2] << (64 - off));
        } else {
            a = Pp[q]; b = Pp[q + 1];
        }
        b &= 0xFFFFULL;
        unsigned long long ra = a, rb = b;
        #pragma unroll
        for (int s = 1; s <= 4; ++s) {
            ra |= a << s;
            rb |= (b << s) | (a >> (64 - s));
        }
        rb &= 0xFFFFULL;
        ro[r * 3 + 0] = (unsigned int)ra;
        ro[r * 3 + 1] = (unsigned int)(ra >> 32);
        ro[r * 3 + 2] = (unsigned int)rb;
    }
    __syncthreads();
    unsigned int zeros = 0;
    for (int i = lane; i < DB_H; i += 64) {
        int lo = (i >= 4) ? i - 4 : 0;
        unsigned int c0 = 0, c1 = 0, c2 = 0;
        for (int ii = lo; ii <= i; ++ii) {
            c0 |= ro[ii * 3 + 0];
            c1 |= ro[ii * 3 + 1];
            c2 |= ro[ii * 3 + 2];
        }
        zeros += 80u - __popc(c0) - __popc(c1) - __popc(c2);
    }
    for (int off = 32; off > 0; off >>= 1)
        zeros += (unsigned int)__shfl_down((int)zeros, off, 64);
    if (lane == 0) atomicAdd(count_zeros, zeros);
}

extern "C" void kernel_launch(void* const* d_in, const int* in_sizes, int n_in,
                              void* d_out, int out_size, void* d_ws, size_t ws_size,
                              hipStream_t stream) {
    const float* x = (const float*)d_in[0];
    const int* mask = (const int*)d_in[1];
    float* out = (float*)d_out;

    unsigned int* counter = (unsigned int*)d_ws;
    unsigned int* bits = (unsigned int*)((char*)d_ws + 16);
    const size_t bits_bytes = (size_t)DB_NPLANES * DB_PLANE_WORDS * 4;
    const bool use_bits = ws_size >= 16 + bits_bytes;

    hipMemsetAsync(d_ws, 0, 16, stream);  // counter reset every call

    if (use_bits) {
        db_mask_kernel<<<DB_NPLANES / PPB, 256, 0, stream>>>(mask, bits, counter);
        db_apply_bits<<<2048, 256, 0, stream>>>(
            (const float4*)x, bits, counter, (float4*)out);
    } else {
        db_count_kernel<<<DB_NPLANES / PPB, 256, 0, stream>>>(mask, counter);
        db_apply_recompute<<<DB_NPLANES / PPB, 256, 0, stream>>>(
            x, mask, counter, out);
    }
}

// Round 3
// 115.919 us; speedup vs baseline: 2.8611x; 1.2345x over previous
//
#include <hip/hip_runtime.h>

// DropBlock, N=64 C=64 H=80 W=80, block_size=5 (top/left-clipped window max).
// Bitboard formulation: seed mask packed 1 bit/elem via __ballot; width-5
// window-OR via 128-bit shifts (row pass) + 5-row OR (col pass).
// R3: one plane per 256-thread block; phase-1 split across the 4 waves
// (25 fully-unrolled load+ballot per wave) to kill the latency chain and
// raise occupancy (grid 1024 -> 4096 blocks).
#define DB_H 80
#define DB_W 80
#define DB_PLANE (DB_H * DB_W)               // 6400
#define DB_NPLANES 4096                      // N*C
#define DB_ROW_WORDS 3                       // 96-bit padded row of block mask
#define DB_PLANE_WORDS (DB_H * DB_ROW_WORDS) // 240
#define DB_TOTAL (DB_PLANE * DB_NPLANES)     // 26214400
#define DB_COUNT_F 26214400.0f               // 25 * 2^20 — exact in f32
#define PPB 4                                // (fallback kernels only)

// Kernel 1: per-plane bitboard window-OR + zero count + packed mask store.
__global__ __launch_bounds__(256) void db_mask_kernel(
    const int* __restrict__ mask,
    unsigned int* __restrict__ bits,
    unsigned int* __restrict__ count_zeros)
{
    __shared__ unsigned long long Pp[104];        // packed seed bits (+pad)
    __shared__ unsigned int ro[DB_PLANE_WORDS];   // row-OR, 3 words/row
    __shared__ unsigned int bm[DB_PLANE_WORDS];   // block mask
    __shared__ unsigned int partial[2];
    const int t = threadIdx.x;
    const int wid = t >> 6, lane = t & 63;
    const int plane = blockIdx.x;
    const int* mp = mask + plane * DB_PLANE;

    // Phase 1: each wave packs 25 qwords (1600 elems), fully unrolled so all
    // 25 coalesced 256B loads are in flight before the first ballot waits.
    #pragma unroll
    for (int k = 0; k < 25; ++k) {
        const int q = wid * 25 + k;
        unsigned long long bal = __ballot(mp[q * 64 + lane] & 1);
        if (lane == 0) Pp[q] = bal;
    }
    if (t < 4) Pp[100 + t] = 0ULL;
    __syncthreads();

    // Phase 2: one row per thread (t<80). Row = 80 bits as 128-bit (b:a);
    // left-clipped width-5 OR: r = OR_{s=0..4} m<<s (zero-fill = clip).
    if (t < DB_H) {
        const int r = t;
        const int bitpos = r * DB_W;
        const int q = bitpos >> 6, off = bitpos & 63;
        unsigned long long a, b;
        if (off) {
            a = (Pp[q] >> off) | (Pp[q + 1] << (64 - off));
            b = (Pp[q + 1] >> off) | (Pp[q + 2] << (64 - off));
        } else {
            a = Pp[q]; b = Pp[q + 1];
        }
        b &= 0xFFFFULL;
        unsigned long long ra = a, rb = b;
        #pragma unroll
        for (int s = 1; s <= 4; ++s) {
            ra |= a << s;
            rb |= (b << s) | (a >> (64 - s));
        }
        rb &= 0xFFFFULL;
        ro[r * 3 + 0] = (unsigned int)ra;
        ro[r * 3 + 1] = (unsigned int)(ra >> 32);
        ro[r * 3 + 2] = (unsigned int)rb;
    }
    __syncthreads();

    // Phase 3: col OR over rows i-4..i (top clip), count zeros, stage bm.
    unsigned int zeros = 0;
    if (t < DB_H) {
        const int i = t;
        const int lo = (i >= 4) ? i - 4 : 0;
        unsigned int c0 = 0, c1 = 0, c2 = 0;
        for (int ii = lo; ii <= i; ++ii) {
            c0 |= ro[ii * 3 + 0];
            c1 |= ro[ii * 3 + 1];
            c2 |= ro[ii * 3 + 2];
        }
        zeros = 80u - __popc(c0) - __popc(c1) - __popc(c2);
        bm[i * 3 + 0] = c0; bm[i * 3 + 1] = c1; bm[i * 3 + 2] = c2;
    }
    for (int off = 32; off > 0; off >>= 1)
        zeros += (unsigned int)__shfl_down((int)zeros, off, 64);
    if (lane == 0 && wid < 2) partial[wid] = zeros;
    __syncthreads();
    if (t == 0) atomicAdd(count_zeros, partial[0] + partial[1]);
    // Coalesced packed-mask store (threads 0..239).
    if (t < DB_PLANE_WORDS) bits[plane * DB_PLANE_WORDS + t] = bm[t];
}

// Kernel 2: out = blocked ? 0 : x * (countM / count_zeros), float4 stream.
__global__ __launch_bounds__(256) void db_apply_bits(
    const float4* __restrict__ x,
    const unsigned int* __restrict__ bits,
    const unsigned int* __restrict__ count_zeros,
    float4* __restrict__ out)
{
    const float scale = DB_COUNT_F / (float)(*count_zeros);
    const int NG = DB_TOTAL / 4;
    const int stride = gridDim.x * blockDim.x;
    for (int g = blockIdx.x * blockDim.x + threadIdx.x; g < NG; g += stride) {
        float4 v = x[g];
        int e = g * 4;
        int plane = e / DB_PLANE;
        int ep = e - plane * DB_PLANE;
        int i = ep / DB_W;
        int j = ep - i * DB_W;   // j % 4 == 0; 4 bits never cross a word
        unsigned int wb =
            bits[plane * DB_PLANE_WORDS + i * 3 + (j >> 5)] >> (j & 31);
        float4 o;
        o.x = (wb & 1u) ? 0.0f : v.x * scale;
        o.y = (wb & 2u) ? 0.0f : v.y * scale;
        o.z = (wb & 4u) ? 0.0f : v.z * scale;
        o.w = (wb & 8u) ? 0.0f : v.w * scale;
        out[g] = o;
    }
}

// ---- Fallback path (ws too small for bits) — unchanged from R2. ----
__global__ __launch_bounds__(256) void db_apply_recompute(
    const float* __restrict__ x,
    const int* __restrict__ mask,
    const unsigned int* __restrict__ count_zeros,
    float* __restrict__ out)
{
    __shared__ unsigned long long P[PPB][104];
    __shared__ unsigned int RO[PPB][DB_PLANE_WORDS];
    const float scale = DB_COUNT_F / (float)(*count_zeros);
    const int wid = threadIdx.x >> 6;
    const int lane = threadIdx.x & 63;
    const int plane = blockIdx.x * PPB + wid;
    const int* mp = mask + plane * DB_PLANE;
    unsigned long long* Pp = P[wid];
    unsigned int* ro = RO[wid];

    #pragma unroll 4
    for (int k = 0; k < 100; ++k) {
        unsigned long long bal = __ballot(mp[k * 64 + lane] & 1);
        if (lane == 0) Pp[k] = bal;
    }
    if (lane < 4) Pp[100 + lane] = 0ULL;
    __syncthreads();
    for (int r = lane; r < DB_H; r += 64) {
        int bitpos = r * DB_W;
        int q = bitpos >> 6, off = bitpos & 63;
        unsigned long long a, b;
        if (off) {
            a = (Pp[q] >> off) | (Pp[q + 1] << (64 - off));
            b = (Pp[q + 1] >> off) | (Pp[q + 2] << (64 - off));
        } else {
            a = Pp[q]; b = Pp[q + 1];
        }
        b &= 0xFFFFULL;
        unsigned long long ra = a, rb = b;
        #pragma unroll
        for (int s = 1; s <= 4; ++s) {
            ra |= a << s;
            rb |= (b << s) | (a >> (64 - s));
        }
        rb &= 0xFFFFULL;
        ro[r * 3 + 0] = (unsigned int)ra;
        ro[r * 3 + 1] = (unsigned int)(ra >> 32);
        ro[r * 3 + 2] = (unsigned int)rb;
    }
    __syncthreads();
    __shared__ unsigned int BM[PPB][DB_PLANE_WORDS];
    unsigned int* bmp = BM[wid];
    for (int i = lane; i < DB_H; i += 64) {
        int lo = (i >= 4) ? i - 4 : 0;
        unsigned int c0 = 0, c1 = 0, c2 = 0;
        for (int ii = lo; ii <= i; ++ii) {
            c0 |= ro[ii * 3 + 0];
            c1 |= ro[ii * 3 + 1];
            c2 |= ro[ii * 3 + 2];
        }
        bmp[i * 3 + 0] = c0; bmp[i * 3 + 1] = c1; bmp[i * 3 + 2] = c2;
    }
    __syncthreads();
    const float* xp = x + plane * DB_PLANE;
    float* op = out + plane * DB_PLANE;
    for (int e = lane; e < DB_PLANE; e += 64) {
        int i = e / DB_W, j = e - i * DB_W;
        unsigned int wb = bmp[i * 3 + (j >> 5)] >> (j & 31);
        op[e] = (wb & 1u) ? 0.0f : xp[e] * scale;
    }
}

__global__ __launch_bounds__(256) void db_count_kernel(
    const int* __restrict__ mask,
    unsigned int* __restrict__ count_zeros)
{
    __shared__ unsigned long long P[PPB][104];
    __shared__ unsigned int RO[PPB][DB_PLANE_WORDS];
    const int wid = threadIdx.x >> 6;
    const int lane = threadIdx.x & 63;
    const int plane = blockIdx.x * PPB + wid;
    const int* mp = mask + plane * DB_PLANE;
    unsigned long long* Pp = P[wid];
    unsigned int* ro = RO[wid];
    #pragma unroll 4
    for (int k = 0; k < 100; ++k) {
        unsigned long long bal = __ballot(mp[k * 64 + lane] & 1);
        if (lane == 0) Pp[k] = bal;
    }
    if (lane < 4) Pp[100 + lane] = 0ULL;
    __syncthreads();
    for (int r = lane; r < DB_H; r += 64) {
        int bitpos = r * DB_W;
        int q = bitpos >> 6, off = bitpos & 63;
        unsigned long long a, b;
        if (off) {
            a = (Pp[q] >> off) | (Pp[q + 1] << (64 - off));
            b = (Pp[q + 1] >> off) | (Pp[q + 2] << (64 - off));
        } else {
            a = Pp[q]; b = Pp[q + 1];
        }
        b &= 0xFFFFULL;
        unsigned long long ra = a, rb = b;
        #pragma unroll
        for (int s = 1; s <= 4; ++s) {
            ra |= a << s;
            rb |= (b << s) | (a >> (64 - s));
        }
        rb &= 0xFFFFULL;
        ro[r * 3 + 0] = (unsigned int)ra;
        ro[r * 3 + 1] = (unsigned int)(ra >> 32);
        ro[r * 3 + 2] = (unsigned int)rb;
    }
    __syncthreads();
    unsigned int zeros = 0;
    for (int i = lane; i < DB_H; i += 64) {
        int lo = (i >= 4) ? i - 4 : 0;
        unsigned int c0 = 0, c1 = 0, c2 = 0;
        for (int ii = lo; ii <= i; ++ii) {
            c0 |= ro[ii * 3 + 0];
            c1 |= ro[ii * 3 + 1];
            c2 |= ro[ii * 3 + 2];
        }
        zeros += 80u - __popc(c0) - __popc(c1) - __popc(c2);
    }
    for (int off = 32; off > 0; off >>= 1)
        zeros += (unsigned int)__shfl_down((int)zeros, off, 64);
    if (lane == 0) atomicAdd(count_zeros, zeros);
}

extern "C" void kernel_launch(void* const* d_in, const int* in_sizes, int n_in,
                              void* d_out, int out_size, void* d_ws, size_t ws_size,
                              hipStream_t stream) {
    const float* x = (const float*)d_in[0];
    const int* mask = (const int*)d_in[1];
    float* out = (float*)d_out;

    unsigned int* counter = (unsigned int*)d_ws;
    unsigned int* bits = (unsigned int*)((char*)d_ws + 16);
    const size_t bits_bytes = (size_t)DB_NPLANES * DB_PLANE_WORDS * 4;
    const bool use_bits = ws_size >= 16 + bits_bytes;

    hipMemsetAsync(d_ws, 0, 16, stream);  // counter reset every call

    if (use_bits) {
        db_mask_kernel<<<DB_NPLANES, 256, 0, stream>>>(mask, bits, counter);
        db_apply_bits<<<2048, 256, 0, stream>>>(
            (const float4*)x, bits, counter, (float4*)out);
    } else {
        db_count_kernel<<<DB_NPLANES / PPB, 256, 0, stream>>>(mask, counter);
        db_apply_recompute<<<DB_NPLANES / PPB, 256, 0, stream>>>(
            x, mask, counter, out);
    }
}

// Round 4
// 85.543 us; speedup vs baseline: 3.8771x; 1.3551x over previous
//
#include <hip/hip_runtime.h>

// DropBlock, N=64 C=64 H=80 W=80, block_size=5 (top/left-clipped window max).
// Bitboard formulation: seed mask packed 1 bit/elem via __ballot; width-5
// window-OR via 128-bit shifts (row pass) + 5-row OR (col pass).
// R4: replace 4096 same-address atomics (serialized at ~20ns each = the 79us
// floor) with 64 cacheline-spread counters; apply kernel reduces the 64.
#define DB_H 80
#define DB_W 80
#define DB_PLANE (DB_H * DB_W)               // 6400
#define DB_NPLANES 4096                      // N*C
#define DB_ROW_WORDS 3                       // 96-bit padded row of block mask
#define DB_PLANE_WORDS (DB_H * DB_ROW_WORDS) // 240
#define DB_TOTAL (DB_PLANE * DB_NPLANES)     // 26214400
#define DB_COUNT_F 26214400.0f               // 25 * 2^20 — exact in f32
#define DB_NCTR 64                           // spread counters
#define DB_CTR_STRIDE 32                     // uints -> 128B apart
#define DB_CTR_BYTES (DB_NCTR * DB_CTR_STRIDE * 4)  // 8192
#define PPB 4                                // (fallback kernels only)

// Kernel 1: per-plane bitboard window-OR + zero count + packed mask store.
__global__ __launch_bounds__(256) void db_mask_kernel(
    const int* __restrict__ mask,
    unsigned int* __restrict__ bits,
    unsigned int* __restrict__ counters)
{
    __shared__ unsigned long long Pp[104];        // packed seed bits (+pad)
    __shared__ unsigned int ro[DB_PLANE_WORDS];   // row-OR, 3 words/row
    __shared__ unsigned int bm[DB_PLANE_WORDS];   // block mask
    __shared__ unsigned int partial[2];
    const int t = threadIdx.x;
    const int wid = t >> 6, lane = t & 63;
    const int plane = blockIdx.x;
    const int* mp = mask + plane * DB_PLANE;

    // Phase 1: each wave packs 25 qwords (1600 elems), fully unrolled so all
    // 25 coalesced 256B loads are in flight before the first ballot waits.
    #pragma unroll
    for (int k = 0; k < 25; ++k) {
        const int q = wid * 25 + k;
        unsigned long long bal = __ballot(mp[q * 64 + lane] & 1);
        if (lane == 0) Pp[q] = bal;
    }
    if (t < 4) Pp[100 + t] = 0ULL;
    __syncthreads();

    // Phase 2: one row per thread (t<80). Row = 80 bits as 128-bit (b:a);
    // left-clipped width-5 OR: r = OR_{s=0..4} m<<s (zero-fill = clip).
    if (t < DB_H) {
        const int r = t;
        const int bitpos = r * DB_W;
        const int q = bitpos >> 6, off = bitpos & 63;
        unsigned long long a, b;
        if (off) {
            a = (Pp[q] >> off) | (Pp[q + 1] << (64 - off));
            b = (Pp[q + 1] >> off) | (Pp[q + 2] << (64 - off));
        } else {
            a = Pp[q]; b = Pp[q + 1];
        }
        b &= 0xFFFFULL;
        unsigned long long ra = a, rb = b;
        #pragma unroll
        for (int s = 1; s <= 4; ++s) {
            ra |= a << s;
            rb |= (b << s) | (a >> (64 - s));
        }
        rb &= 0xFFFFULL;
        ro[r * 3 + 0] = (unsigned int)ra;
        ro[r * 3 + 1] = (unsigned int)(ra >> 32);
        ro[r * 3 + 2] = (unsigned int)rb;
    }
    __syncthreads();

    // Phase 3: col OR over rows i-4..i (top clip), count zeros, stage bm.
    unsigned int zeros = 0;
    if (t < DB_H) {
        const int i = t;
        const int lo = (i >= 4) ? i - 4 : 0;
        unsigned int c0 = 0, c1 = 0, c2 = 0;
        for (int ii = lo; ii <= i; ++ii) {
            c0 |= ro[ii * 3 + 0];
            c1 |= ro[ii * 3 + 1];
            c2 |= ro[ii * 3 + 2];
        }
        zeros = 80u - __popc(c0) - __popc(c1) - __popc(c2);
        bm[i * 3 + 0] = c0; bm[i * 3 + 1] = c1; bm[i * 3 + 2] = c2;
    }
    for (int off = 32; off > 0; off >>= 1)
        zeros += (unsigned int)__shfl_down((int)zeros, off, 64);
    if (lane == 0 && wid < 2) partial[wid] = zeros;
    __syncthreads();
    // One atomic per block, spread over 64 cacheline-separated counters.
    if (t == 0)
        atomicAdd(&counters[(blockIdx.x & (DB_NCTR - 1)) * DB_CTR_STRIDE],
                  partial[0] + partial[1]);
    // Coalesced packed-mask store (threads 0..239).
    if (t < DB_PLANE_WORDS) bits[plane * DB_PLANE_WORDS + t] = bm[t];
}

// Kernel 2: out = blocked ? 0 : x * (countM / count_zeros), float4 stream.
__global__ __launch_bounds__(256) void db_apply_bits(
    const float4* __restrict__ x,
    const unsigned int* __restrict__ bits,
    const unsigned int* __restrict__ counters,
    float4* __restrict__ out)
{
    __shared__ float s_scale;
    if (threadIdx.x < DB_NCTR) {
        unsigned int c = counters[threadIdx.x * DB_CTR_STRIDE];
        for (int off = 32; off > 0; off >>= 1)
            c += (unsigned int)__shfl_down((int)c, off, 64);
        if (threadIdx.x == 0) s_scale = DB_COUNT_F / (float)c;
    }
    __syncthreads();
    const float scale = s_scale;
    const int NG = DB_TOTAL / 4;
    const int stride = gridDim.x * blockDim.x;
    for (int g = blockIdx.x * blockDim.x + threadIdx.x; g < NG; g += stride) {
        float4 v = x[g];
        int e = g * 4;
        int plane = e / DB_PLANE;
        int ep = e - plane * DB_PLANE;
        int i = ep / DB_W;
        int j = ep - i * DB_W;   // j % 4 == 0; 4 bits never cross a word
        unsigned int wb =
            bits[plane * DB_PLANE_WORDS + i * 3 + (j >> 5)] >> (j & 31);
        float4 o;
        o.x = (wb & 1u) ? 0.0f : v.x * scale;
        o.y = (wb & 2u) ? 0.0f : v.y * scale;
        o.z = (wb & 4u) ? 0.0f : v.z * scale;
        o.w = (wb & 8u) ? 0.0f : v.w * scale;
        out[g] = o;
    }
}

// ---- Fallback path (ws too small for bits). ----
__global__ __launch_bounds__(256) void db_apply_recompute(
    const float* __restrict__ x,
    const int* __restrict__ mask,
    const unsigned int* __restrict__ counters,
    float* __restrict__ out)
{
    __shared__ unsigned long long P[PPB][104];
    __shared__ unsigned int RO[PPB][DB_PLANE_WORDS];
    __shared__ float s_scale;
    if (threadIdx.x < DB_NCTR) {
        unsigned int c = counters[threadIdx.x * DB_CTR_STRIDE];
        for (int off = 32; off > 0; off >>= 1)
            c += (unsigned int)__shfl_down((int)c, off, 64);
        if (threadIdx.x == 0) s_scale = DB_COUNT_F / (float)c;
    }
    __syncthreads();
    const float scale = s_scale;
    const int wid = threadIdx.x >> 6;
    const int lane = threadIdx.x & 63;
    const int plane = blockIdx.x * PPB + wid;
    const int* mp = mask + plane * DB_PLANE;
    unsigned long long* Pp = P[wid];
    unsigned int* ro = RO[wid];

    #pragma unroll 4
    for (int k = 0; k < 100; ++k) {
        unsigned long long bal = __ballot(mp[k * 64 + lane] & 1);
        if (lane == 0) Pp[k] = bal;
    }
    if (lane < 4) Pp[100 + lane] = 0ULL;
    __syncthreads();
    for (int r = lane; r < DB_H; r += 64) {
        int bitpos = r * DB_W;
        int q = bitpos >> 6, off = bitpos & 63;
        unsigned long long a, b;
        if (off) {
            a = (Pp[q] >> off) | (Pp[q + 1] << (64 - off));
            b = (Pp[q + 1] >> off) | (Pp[q + 2] << (64 - off));
        } else {
            a = Pp[q]; b = Pp[q + 1];
        }
        b &= 0xFFFFULL;
        unsigned long long ra = a, rb = b;
        #pragma unroll
        for (int s = 1; s <= 4; ++s) {
            ra |= a << s;
            rb |= (b << s) | (a >> (64 - s));
        }
        rb &= 0xFFFFULL;
        ro[r * 3 + 0] = (unsigned int)ra;
        ro[r * 3 + 1] = (unsigned int)(ra >> 32);
        ro[r * 3 + 2] = (unsigned int)rb;
    }
    __syncthreads();
    __shared__ unsigned int BM[PPB][DB_PLANE_WORDS];
    unsigned int* bmp = BM[wid];
    for (int i = lane; i < DB_H; i += 64) {
        int lo = (i >= 4) ? i - 4 : 0;
        unsigned int c0 = 0, c1 = 0, c2 = 0;
        for (int ii = lo; ii <= i; ++ii) {
            c0 |= ro[ii * 3 + 0];
            c1 |= ro[ii * 3 + 1];
            c2 |= ro[ii * 3 + 2];
        }
        bmp[i * 3 + 0] = c0; bmp[i * 3 + 1] = c1; bmp[i * 3 + 2] = c2;
    }
    __syncthreads();
    const float* xp = x + plane * DB_PLANE;
    float* op = out + plane * DB_PLANE;
    for (int e = lane; e < DB_PLANE; e += 64) {
        int i = e / DB_W, j = e - i * DB_W;
        unsigned int wb = bmp[i * 3 + (j >> 5)] >> (j & 31);
        op[e] = (wb & 1u) ? 0.0f : xp[e] * scale;
    }
}

__global__ __launch_bounds__(256) void db_count_kernel(
    const int* __restrict__ mask,
    unsigned int* __restrict__ counters)
{
    __shared__ unsigned long long P[PPB][104];
    __shared__ unsigned int RO[PPB][DB_PLANE_WORDS];
    const int wid = threadIdx.x >> 6;
    const int lane = threadIdx.x & 63;
    const int plane = blockIdx.x * PPB + wid;
    const int* mp = mask + plane * DB_PLANE;
    unsigned long long* Pp = P[wid];
    unsigned int* ro = RO[wid];
    #pragma unroll 4
    for (int k = 0; k < 100; ++k) {
        unsigned long long bal = __ballot(mp[k * 64 + lane] & 1);
        if (lane == 0) Pp[k] = bal;
    }
    if (lane < 4) Pp[100 + lane] = 0ULL;
    __syncthreads();
    for (int r = lane; r < DB_H; r += 64) {
        int bitpos = r * DB_W;
        int q = bitpos >> 6, off = bitpos & 63;
        unsigned long long a, b;
        if (off) {
            a = (Pp[q] >> off) | (Pp[q + 1] << (64 - off));
            b = (Pp[q + 1] >> off) | (Pp[q + 2] << (64 - off));
        } else {
            a = Pp[q]; b = Pp[q + 1];
        }
        b &= 0xFFFFULL;
        unsigned long long ra = a, rb = b;
        #pragma unroll
        for (int s = 1; s <= 4; ++s) {
            ra |= a << s;
            rb |= (b << s) | (a >> (64 - s));
        }
        rb &= 0xFFFFULL;
        ro[r * 3 + 0] = (unsigned int)ra;
        ro[r * 3 + 1] = (unsigned int)(ra >> 32);
        ro[r * 3 + 2] = (unsigned int)rb;
    }
    __syncthreads();
    unsigned int zeros = 0;
    for (int i = lane; i < DB_H; i += 64) {
        int lo = (i >= 4) ? i - 4 : 0;
        unsigned int c0 = 0, c1 = 0, c2 = 0;
        for (int ii = lo; ii <= i; ++ii) {
            c0 |= ro[ii * 3 + 0];
            c1 |= ro[ii * 3 + 1];
            c2 |= ro[ii * 3 + 2];
        }
        zeros += 80u - __popc(c0) - __popc(c1) - __popc(c2);
    }
    for (int off = 32; off > 0; off >>= 1)
        zeros += (unsigned int)__shfl_down((int)zeros, off, 64);
    if (lane == 0)
        atomicAdd(&counters[((blockIdx.x * PPB + wid) & (DB_NCTR - 1)) *
                            DB_CTR_STRIDE], zeros);
}

extern "C" void kernel_launch(void* const* d_in, const int* in_sizes, int n_in,
                              void* d_out, int out_size, void* d_ws, size_t ws_size,
                              hipStream_t stream) {
    const float* x = (const float*)d_in[0];
    const int* mask = (const int*)d_in[1];
    float* out = (float*)d_out;

    unsigned int* counters = (unsigned int*)d_ws;
    unsigned int* bits = (unsigned int*)((char*)d_ws + DB_CTR_BYTES);
    const size_t bits_bytes = (size_t)DB_NPLANES * DB_PLANE_WORDS * 4;
    const bool use_bits = ws_size >= DB_CTR_BYTES + bits_bytes;

    hipMemsetAsync(d_ws, 0, DB_CTR_BYTES, stream);  // counters reset each call

    if (use_bits) {
        db_mask_kernel<<<DB_NPLANES, 256, 0, stream>>>(mask, bits, counters);
        db_apply_bits<<<2048, 256, 0, stream>>>(
            (const float4*)x, bits, counters, (float4*)out);
    } else {
        db_count_kernel<<<DB_NPLANES / PPB, 256, 0, stream>>>(mask, counters);
        db_apply_recompute<<<DB_NPLANES / PPB, 256, 0, stream>>>(
            x, mask, counters, out);
    }
}

// Round 5
// 79.745 us; speedup vs baseline: 4.1590x; 1.0727x over previous
//
#include <hip/hip_runtime.h>

// DropBlock, N=64 C=64 H=80 W=80, block_size=5 (top/left-clipped window max).
// Bitboard formulation: seed mask packed 1 bit/elem via __ballot; width-5
// window-OR via 128-bit shifts (row pass) + 5-row OR (col pass).
// R5: no atomics, no memset in the graph. Mask kernel plain-stores
// counts[plane]; apply kernel sums the 4096 counts in its prologue.
// (R4 lesson: an 8KB hipMemsetAsync node costs ~60us per graph replay.)
#define DB_H 80
#define DB_W 80
#define DB_PLANE (DB_H * DB_W)               // 6400
#define DB_NPLANES 4096                      // N*C
#define DB_ROW_WORDS 3                       // 96-bit padded row of block mask
#define DB_PLANE_WORDS (DB_H * DB_ROW_WORDS) // 240
#define DB_TOTAL (DB_PLANE * DB_NPLANES)     // 26214400
#define DB_COUNT_F 26214400.0f               // 25 * 2^20 — exact in f32
#define DB_CNT_BYTES (DB_NPLANES * 4)        // 16384
#define PPB 4                                // (fallback kernels only)

// Kernel 1: per-plane bitboard window-OR + zero count + packed mask store.
__global__ __launch_bounds__(256) void db_mask_kernel(
    const int* __restrict__ mask,
    unsigned int* __restrict__ bits,
    unsigned int* __restrict__ counts)
{
    __shared__ unsigned long long Pp[104];        // packed seed bits (+pad)
    __shared__ unsigned int ro[DB_PLANE_WORDS];   // row-OR, 3 words/row
    __shared__ unsigned int bm[DB_PLANE_WORDS];   // block mask
    __shared__ unsigned int partial[2];
    const int t = threadIdx.x;
    const int wid = t >> 6, lane = t & 63;
    const int plane = blockIdx.x;
    const int* mp = mask + plane * DB_PLANE;

    // Phase 1: each wave packs 25 qwords (1600 elems), fully unrolled so all
    // 25 coalesced 256B loads are in flight before the first ballot waits.
    #pragma unroll
    for (int k = 0; k < 25; ++k) {
        const int q = wid * 25 + k;
        unsigned long long bal = __ballot(mp[q * 64 + lane] & 1);
        if (lane == 0) Pp[q] = bal;
    }
    if (t < 4) Pp[100 + t] = 0ULL;
    __syncthreads();

    // Phase 2: one row per thread (t<80). Row = 80 bits as 128-bit (b:a);
    // left-clipped width-5 OR: r = OR_{s=0..4} m<<s (zero-fill = clip).
    if (t < DB_H) {
        const int r = t;
        const int bitpos = r * DB_W;
        const int q = bitpos >> 6, off = bitpos & 63;
        unsigned long long a, b;
        if (off) {
            a = (Pp[q] >> off) | (Pp[q + 1] << (64 - off));
            b = (Pp[q + 1] >> off) | (Pp[q + 2] << (64 - off));
        } else {
            a = Pp[q]; b = Pp[q + 1];
        }
        b &= 0xFFFFULL;
        unsigned long long ra = a, rb = b;
        #pragma unroll
        for (int s = 1; s <= 4; ++s) {
            ra |= a << s;
            rb |= (b << s) | (a >> (64 - s));
        }
        rb &= 0xFFFFULL;
        ro[r * 3 + 0] = (unsigned int)ra;
        ro[r * 3 + 1] = (unsigned int)(ra >> 32);
        ro[r * 3 + 2] = (unsigned int)rb;
    }
    __syncthreads();

    // Phase 3: col OR over rows i-4..i (top clip), count zeros, stage bm.
    unsigned int zeros = 0;
    if (t < DB_H) {
        const int i = t;
        const int lo = (i >= 4) ? i - 4 : 0;
        unsigned int c0 = 0, c1 = 0, c2 = 0;
        for (int ii = lo; ii <= i; ++ii) {
            c0 |= ro[ii * 3 + 0];
            c1 |= ro[ii * 3 + 1];
            c2 |= ro[ii * 3 + 2];
        }
        zeros = 80u - __popc(c0) - __popc(c1) - __popc(c2);
        bm[i * 3 + 0] = c0; bm[i * 3 + 1] = c1; bm[i * 3 + 2] = c2;
    }
    for (int off = 32; off > 0; off >>= 1)
        zeros += (unsigned int)__shfl_down((int)zeros, off, 64);
    if (lane == 0 && wid < 2) partial[wid] = zeros;
    __syncthreads();
    // Plain per-plane store — every slot written every call, no init needed.
    if (t == 0) counts[plane] = partial[0] + partial[1];
    // Coalesced packed-mask store (threads 0..239).
    if (t < DB_PLANE_WORDS) bits[plane * DB_PLANE_WORDS + t] = bm[t];
}

// Kernel 2: out = blocked ? 0 : x * (countM / count_zeros), float4 stream.
// Prologue: block-local sum of the 4096 per-plane counts (L3-hit, ~16KB).
__global__ __launch_bounds__(256) void db_apply_bits(
    const float4* __restrict__ x,
    const unsigned int* __restrict__ bits,
    const unsigned int* __restrict__ counts,
    float4* __restrict__ out)
{
    __shared__ float s_scale;
    __shared__ unsigned int s_part[4];
    {
        const uint4* cp = (const uint4*)counts;   // 1024 uint4
        unsigned int c = 0;
        #pragma unroll
        for (int k = 0; k < 4; ++k) {
            uint4 v = cp[k * 256 + threadIdx.x];
            c += v.x + v.y + v.z + v.w;
        }
        for (int off = 32; off > 0; off >>= 1)
            c += (unsigned int)__shfl_down((int)c, off, 64);
        if ((threadIdx.x & 63) == 0) s_part[threadIdx.x >> 6] = c;
        __syncthreads();
        if (threadIdx.x == 0)
            s_scale = DB_COUNT_F /
                      (float)(s_part[0] + s_part[1] + s_part[2] + s_part[3]);
        __syncthreads();
    }
    const float scale = s_scale;
    const int NG = DB_TOTAL / 4;
    const int stride = gridDim.x * blockDim.x;
    for (int g = blockIdx.x * blockDim.x + threadIdx.x; g < NG; g += stride) {
        float4 v = x[g];
        int e = g * 4;
        int plane = e / DB_PLANE;
        int ep = e - plane * DB_PLANE;
        int i = ep / DB_W;
        int j = ep - i * DB_W;   // j % 4 == 0; 4 bits never cross a word
        unsigned int wb =
            bits[plane * DB_PLANE_WORDS + i * 3 + (j >> 5)] >> (j & 31);
        float4 o;
        o.x = (wb & 1u) ? 0.0f : v.x * scale;
        o.y = (wb & 2u) ? 0.0f : v.y * scale;
        o.z = (wb & 4u) ? 0.0f : v.z * scale;
        o.w = (wb & 8u) ? 0.0f : v.w * scale;
        out[g] = o;
    }
}

// ---- Fallback path (ws too small for bits). ----
__global__ __launch_bounds__(256) void db_count_kernel(
    const int* __restrict__ mask,
    unsigned int* __restrict__ counts)
{
    __shared__ unsigned long long P[PPB][104];
    __shared__ unsigned int RO[PPB][DB_PLANE_WORDS];
    const int wid = threadIdx.x >> 6;
    const int lane = threadIdx.x & 63;
    const int plane = blockIdx.x * PPB + wid;
    const int* mp = mask + plane * DB_PLANE;
    unsigned long long* Pp = P[wid];
    unsigned int* ro = RO[wid];
    #pragma unroll 4
    for (int k = 0; k < 100; ++k) {
        unsigned long long bal = __ballot(mp[k * 64 + lane] & 1);
        if (lane == 0) Pp[k] = bal;
    }
    if (lane < 4) Pp[100 + lane] = 0ULL;
    __syncthreads();
    for (int r = lane; r < DB_H; r += 64) {
        int bitpos = r * DB_W;
        int q = bitpos >> 6, off = bitpos & 63;
        unsigned long long a, b;
        if (off) {
            a = (Pp[q] >> off) | (Pp[q + 1] << (64 - off));
            b = (Pp[q + 1] >> off) | (Pp[q + 2] << (64 - off));
        } else {
            a = Pp[q]; b = Pp[q + 1];
        }
        b &= 0xFFFFULL;
        unsigned long long ra = a, rb = b;
        #pragma unroll
        for (int s = 1; s <= 4; ++s) {
            ra |= a << s;
            rb |= (b << s) | (a >> (64 - s));
        }
        rb &= 0xFFFFULL;
        ro[r * 3 + 0] = (unsigned int)ra;
        ro[r * 3 + 1] = (unsigned int)(ra >> 32);
        ro[r * 3 + 2] = (unsigned int)rb;
    }
    __syncthreads();
    unsigned int zeros = 0;
    for (int i = lane; i < DB_H; i += 64) {
        int lo = (i >= 4) ? i - 4 : 0;
        unsigned int c0 = 0, c1 = 0, c2 = 0;
        for (int ii = lo; ii <= i; ++ii) {
            c0 |= ro[ii * 3 + 0];
            c1 |= ro[ii * 3 + 1];
            c2 |= ro[ii * 3 + 2];
        }
        zeros += 80u - __popc(c0) - __popc(c1) - __popc(c2);
    }
    for (int off = 32; off > 0; off >>= 1)
        zeros += (unsigned int)__shfl_down((int)zeros, off, 64);
    if (lane == 0) counts[plane] = zeros;
}

__global__ __launch_bounds__(256) void db_apply_recompute(
    const float* __restrict__ x,
    const int* __restrict__ mask,
    const unsigned int* __restrict__ counts,
    float* __restrict__ out)
{
    __shared__ unsigned long long P[PPB][104];
    __shared__ unsigned int RO[PPB][DB_PLANE_WORDS];
    __shared__ float s_scale;
    __shared__ unsigned int s_part[4];
    {
        const uint4* cp = (const uint4*)counts;
        unsigned int c = 0;
        #pragma unroll
        for (int k = 0; k < 4; ++k) {
            uint4 v = cp[k * 256 + threadIdx.x];
            c += v.x + v.y + v.z + v.w;
        }
        for (int off = 32; off > 0; off >>= 1)
            c += (unsigned int)__shfl_down((int)c, off, 64);
        if ((threadIdx.x & 63) == 0) s_part[threadIdx.x >> 6] = c;
        __syncthreads();
        if (threadIdx.x == 0)
            s_scale = DB_COUNT_F /
                      (float)(s_part[0] + s_part[1] + s_part[2] + s_part[3]);
        __syncthreads();
    }
    const float scale = s_scale;
    const int wid = threadIdx.x >> 6;
    const int lane = threadIdx.x & 63;
    const int plane = blockIdx.x * PPB + wid;
    const int* mp = mask + plane * DB_PLANE;
    unsigned long long* Pp = P[wid];
    unsigned int* ro = RO[wid];

    #pragma unroll 4
    for (int k = 0; k < 100; ++k) {
        unsigned long long bal = __ballot(mp[k * 64 + lane] & 1);
        if (lane == 0) Pp[k] = bal;
    }
    if (lane < 4) Pp[100 + lane] = 0ULL;
    __syncthreads();
    for (int r = lane; r < DB_H; r += 64) {
        int bitpos = r * DB_W;
        int q = bitpos >> 6, off = bitpos & 63;
        unsigned long long a, b;
        if (off) {
            a = (Pp[q] >> off) | (Pp[q + 1] << (64 - off));
            b = (Pp[q + 1] >> off) | (Pp[q + 2] << (64 - off));
        } else {
            a = Pp[q]; b = Pp[q + 1];
        }
        b &= 0xFFFFULL;
        unsigned long long ra = a, rb = b;
        #pragma unroll
        for (int s = 1; s <= 4; ++s) {
            ra |= a << s;
            rb |= (b << s) | (a >> (64 - s));
        }
        rb &= 0xFFFFULL;
        ro[r * 3 + 0] = (unsigned int)ra;
        ro[r * 3 + 1] = (unsigned int)(ra >> 32);
        ro[r * 3 + 2] = (unsigned int)rb;
    }
    __syncthreads();
    __shared__ unsigned int BM[PPB][DB_PLANE_WORDS];
    unsigned int* bmp = BM[wid];
    for (int i = lane; i < DB_H; i += 64) {
        int lo = (i >= 4) ? i - 4 : 0;
        unsigned int c0 = 0, c1 = 0, c2 = 0;
        for (int ii = lo; ii <= i; ++ii) {
            c0 |= ro[ii * 3 + 0];
            c1 |= ro[ii * 3 + 1];
            c2 |= ro[ii * 3 + 2];
        }
        bmp[i * 3 + 0] = c0; bmp[i * 3 + 1] = c1; bmp[i * 3 + 2] = c2;
    }
    __syncthreads();
    const float* xp = x + plane * DB_PLANE;
    float* op = out + plane * DB_PLANE;
    for (int e = lane; e < DB_PLANE; e += 64) {
        int i = e / DB_W, j = e - i * DB_W;
        unsigned int wb = bmp[i * 3 + (j >> 5)] >> (j & 31);
        op[e] = (wb & 1u) ? 0.0f : xp[e] * scale;
    }
}

extern "C" void kernel_launch(void* const* d_in, const int* in_sizes, int n_in,
                              void* d_out, int out_size, void* d_ws, size_t ws_size,
                              hipStream_t stream) {
    const float* x = (const float*)d_in[0];
    const int* mask = (const int*)d_in[1];
    float* out = (float*)d_out;

    unsigned int* counts = (unsigned int*)d_ws;
    unsigned int* bits = (unsigned int*)((char*)d_ws + DB_CNT_BYTES);
    const size_t bits_bytes = (size_t)DB_NPLANES * DB_PLANE_WORDS * 4;
    const bool use_bits = ws_size >= DB_CNT_BYTES + bits_bytes;

    if (use_bits) {
        db_mask_kernel<<<DB_NPLANES, 256, 0, stream>>>(mask, bits, counts);
        db_apply_bits<<<2048, 256, 0, stream>>>(
            (const float4*)x, bits, counts, (float4*)out);
    } else {
        db_count_kernel<<<DB_NPLANES / PPB, 256, 0, stream>>>(mask, counts);
        db_apply_recompute<<<DB_NPLANES / PPB, 256, 0, stream>>>(
            x, mask, counts, out);
    }
}

// Round 6
// 66.113 us; speedup vs baseline: 5.0165x; 1.2062x over previous
//
#include <hip/hip_runtime.h>

// DropBlock, N=64 C=64 H=80 W=80, block_size=5 (top/left-clipped window max).
// Bitboard formulation: seed mask packed 1 bit/elem via __ballot; width-5
// window-OR via 128-bit shifts (row pass) + 5-row OR (col pass).
// R6: mask kernel restructured — register-hoisted load bursts (25 in flight;
// R5's VGPR=20 proved the compiler interleaved load->ballot, serializing ~25
// HBM latencies per wave), wave-per-plane with 4 planes/block (1024 blocks,
// fully co-resident), wave-local phases, 2 barriers, plain stores (no atomics,
// no memset in graph — R4/R5 lessons).
#define DB_H 80
#define DB_W 80
#define DB_PLANE (DB_H * DB_W)               // 6400
#define DB_NPLANES 4096                      // N*C
#define DB_ROW_WORDS 3                       // 96-bit padded row of block mask
#define DB_PLANE_WORDS (DB_H * DB_ROW_WORDS) // 240
#define DB_TOTAL (DB_PLANE * DB_NPLANES)     // 26214400
#define DB_COUNT_F 26214400.0f               // 25 * 2^20 — exact in f32
#define DB_CNT_BYTES (DB_NPLANES * 4)        // 16384
#define WPB 4                                // waves (planes) per block

// Kernel 1: per-plane bitboard window-OR + zero count + packed mask store.
__global__ __launch_bounds__(256) void db_mask_kernel(
    const int* __restrict__ mask,
    unsigned int* __restrict__ bits,
    unsigned int* __restrict__ counts)
{
    __shared__ unsigned long long P[WPB][104];        // packed seed bits (+pad)
    __shared__ unsigned int RO[WPB][DB_PLANE_WORDS];  // row-OR, 3 words/row
    const int wid = threadIdx.x >> 6, lane = threadIdx.x & 63;
    const int plane = blockIdx.x * WPB + wid;
    const int* mp = mask + plane * DB_PLANE;
    unsigned long long* Pp = P[wid];
    unsigned int* ro = RO[wid];

    // Phase 1: pack 100 qwords in 4 chunks; each chunk loads 25 ints into a
    // REGISTER ARRAY first (forces 25 loads in flight), then ballots.
    #pragma unroll
    for (int c = 0; c < 4; ++c) {
        int v[25];
        #pragma unroll
        for (int k = 0; k < 25; ++k) v[k] = mp[(c * 25 + k) * 64 + lane];
        #pragma unroll
        for (int k = 0; k < 25; ++k) {
            unsigned long long bal = __ballot(v[k] & 1);
            if (lane == 0) Pp[c * 25 + k] = bal;
        }
    }
    if (lane < 4) Pp[100 + lane] = 0ULL;
    __syncthreads();

    // Phase 2: row sliding-OR (width 5, left-clipped), 80 rows over 2 passes.
    // Row = 80 bits as 128-bit (b:a); r = OR_{s=0..4} m<<s (zero-fill = clip).
    for (int r = lane; r < DB_H; r += 64) {
        const int bitpos = r * DB_W;
        const int q = bitpos >> 6, off = bitpos & 63;
        unsigned long long a, b;
        if (off) {
            a = (Pp[q] >> off) | (Pp[q + 1] << (64 - off));
            b = (Pp[q + 1] >> off) | (Pp[q + 2] << (64 - off));
        } else {
            a = Pp[q]; b = Pp[q + 1];
        }
        b &= 0xFFFFULL;
        unsigned long long ra = a, rb = b;
        #pragma unroll
        for (int s = 1; s <= 4; ++s) {
            ra |= a << s;
            rb |= (b << s) | (a >> (64 - s));
        }
        rb &= 0xFFFFULL;
        ro[r * 3 + 0] = (unsigned int)ra;
        ro[r * 3 + 1] = (unsigned int)(ra >> 32);
        ro[r * 3 + 2] = (unsigned int)rb;
    }
    __syncthreads();

    // Phase 3: col OR over rows i-4..i (top clip), count zeros, store bits
    // directly from registers (3.9 MB total — trivial vs the 105 MB read).
    unsigned int zeros = 0;
    for (int i = lane; i < DB_H; i += 64) {
        const int lo = (i >= 4) ? i - 4 : 0;
        unsigned int c0 = 0, c1 = 0, c2 = 0;
        for (int ii = lo; ii <= i; ++ii) {
            c0 |= ro[ii * 3 + 0];
            c1 |= ro[ii * 3 + 1];
            c2 |= ro[ii * 3 + 2];
        }
        zeros += 80u - __popc(c0) - __popc(c1) - __popc(c2);
        unsigned int* bp = bits + plane * DB_PLANE_WORDS + i * 3;
        bp[0] = c0; bp[1] = c1; bp[2] = c2;
    }
    for (int off = 32; off > 0; off >>= 1)
        zeros += (unsigned int)__shfl_down((int)zeros, off, 64);
    if (lane == 0) counts[plane] = zeros;   // plain store, no init needed
}

// Kernel 2: out = blocked ? 0 : x * (countM / count_zeros), float4 stream.
// Prologue: block-local sum of the 4096 per-plane counts (L3-hit, 16KB).
__global__ __launch_bounds__(256) void db_apply_bits(
    const float4* __restrict__ x,
    const unsigned int* __restrict__ bits,
    const unsigned int* __restrict__ counts,
    float4* __restrict__ out)
{
    __shared__ float s_scale;
    __shared__ unsigned int s_part[4];
    {
        const uint4* cp = (const uint4*)counts;   // 1024 uint4
        unsigned int c = 0;
        #pragma unroll
        for (int k = 0; k < 4; ++k) {
            uint4 v = cp[k * 256 + threadIdx.x];
            c += v.x + v.y + v.z + v.w;
        }
        for (int off = 32; off > 0; off >>= 1)
            c += (unsigned int)__shfl_down((int)c, off, 64);
        if ((threadIdx.x & 63) == 0) s_part[threadIdx.x >> 6] = c;
        __syncthreads();
        if (threadIdx.x == 0)
            s_scale = DB_COUNT_F /
                      (float)(s_part[0] + s_part[1] + s_part[2] + s_part[3]);
        __syncthreads();
    }
    const float scale = s_scale;
    const int NG = DB_TOTAL / 4;
    const int stride = gridDim.x * blockDim.x;
    #pragma unroll 2
    for (int g = blockIdx.x * blockDim.x + threadIdx.x; g < NG; g += stride) {
        float4 v = x[g];
        int e = g * 4;
        int plane = e / DB_PLANE;
        int ep = e - plane * DB_PLANE;
        int i = ep / DB_W;
        int j = ep - i * DB_W;   // j % 4 == 0; 4 bits never cross a word
        unsigned int wb =
            bits[plane * DB_PLANE_WORDS + i * 3 + (j >> 5)] >> (j & 31);
        float4 o;
        o.x = (wb & 1u) ? 0.0f : v.x * scale;
        o.y = (wb & 2u) ? 0.0f : v.y * scale;
        o.z = (wb & 4u) ? 0.0f : v.z * scale;
        o.w = (wb & 8u) ? 0.0f : v.w * scale;
        out[g] = o;
    }
}

// ---- Fallback path (ws too small for bits). ----
__global__ __launch_bounds__(256) void db_count_kernel(
    const int* __restrict__ mask,
    unsigned int* __restrict__ counts)
{
    __shared__ unsigned long long P[WPB][104];
    __shared__ unsigned int RO[WPB][DB_PLANE_WORDS];
    const int wid = threadIdx.x >> 6, lane = threadIdx.x & 63;
    const int plane = blockIdx.x * WPB + wid;
    const int* mp = mask + plane * DB_PLANE;
    unsigned long long* Pp = P[wid];
    unsigned int* ro = RO[wid];
    #pragma unroll
    for (int c = 0; c < 4; ++c) {
        int v[25];
        #pragma unroll
        for (int k = 0; k < 25; ++k) v[k] = mp[(c * 25 + k) * 64 + lane];
        #pragma unroll
        for (int k = 0; k < 25; ++k) {
            unsigned long long bal = __ballot(v[k] & 1);
            if (lane == 0) Pp[c * 25 + k] = bal;
        }
    }
    if (lane < 4) Pp[100 + lane] = 0ULL;
    __syncthreads();
    for (int r = lane; r < DB_H; r += 64) {
        const int bitpos = r * DB_W;
        const int q = bitpos >> 6, off = bitpos & 63;
        unsigned long long a, b;
        if (off) {
            a = (Pp[q] >> off) | (Pp[q + 1] << (64 - off));
            b = (Pp[q + 1] >> off) | (Pp[q + 2] << (64 - off));
        } else {
            a = Pp[q]; b = Pp[q + 1];
        }
        b &= 0xFFFFULL;
        unsigned long long ra = a, rb = b;
        #pragma unroll
        for (int s = 1; s <= 4; ++s) {
            ra |= a << s;
            rb |= (b << s) | (a >> (64 - s));
        }
        rb &= 0xFFFFULL;
        ro[r * 3 + 0] = (unsigned int)ra;
        ro[r * 3 + 1] = (unsigned int)(ra >> 32);
        ro[r * 3 + 2] = (unsigned int)rb;
    }
    __syncthreads();
    unsigned int zeros = 0;
    for (int i = lane; i < DB_H; i += 64) {
        const int lo = (i >= 4) ? i - 4 : 0;
        unsigned int c0 = 0, c1 = 0, c2 = 0;
        for (int ii = lo; ii <= i; ++ii) {
            c0 |= ro[ii * 3 + 0];
            c1 |= ro[ii * 3 + 1];
            c2 |= ro[ii * 3 + 2];
        }
        zeros += 80u - __popc(c0) - __popc(c1) - __popc(c2);
    }
    for (int off = 32; off > 0; off >>= 1)
        zeros += (unsigned int)__shfl_down((int)zeros, off, 64);
    if (lane == 0) counts[plane] = zeros;
}

__global__ __launch_bounds__(256) void db_apply_recompute(
    const float* __restrict__ x,
    const int* __restrict__ mask,
    const unsigned int* __restrict__ counts,
    float* __restrict__ out)
{
    __shared__ unsigned long long P[WPB][104];
    __shared__ unsigned int RO[WPB][DB_PLANE_WORDS];
    __shared__ unsigned int BM[WPB][DB_PLANE_WORDS];
    __shared__ float s_scale;
    __shared__ unsigned int s_part[4];
    {
        const uint4* cp = (const uint4*)counts;
        unsigned int c = 0;
        #pragma unroll
        for (int k = 0; k < 4; ++k) {
            uint4 v = cp[k * 256 + threadIdx.x];
            c += v.x + v.y + v.z + v.w;
        }
        for (int off = 32; off > 0; off >>= 1)
            c += (unsigned int)__shfl_down((int)c, off, 64);
        if ((threadIdx.x & 63) == 0) s_part[threadIdx.x >> 6] = c;
        __syncthreads();
        if (threadIdx.x == 0)
            s_scale = DB_COUNT_F /
                      (float)(s_part[0] + s_part[1] + s_part[2] + s_part[3]);
        __syncthreads();
    }
    const float scale = s_scale;
    const int wid = threadIdx.x >> 6, lane = threadIdx.x & 63;
    const int plane = blockIdx.x * WPB + wid;
    const int* mp = mask + plane * DB_PLANE;
    unsigned long long* Pp = P[wid];
    unsigned int* ro = RO[wid];
    #pragma unroll
    for (int c = 0; c < 4; ++c) {
        int v[25];
        #pragma unroll
        for (int k = 0; k < 25; ++k) v[k] = mp[(c * 25 + k) * 64 + lane];
        #pragma unroll
        for (int k = 0; k < 25; ++k) {
            unsigned long long bal = __ballot(v[k] & 1);
            if (lane == 0) Pp[c * 25 + k] = bal;
        }
    }
    if (lane < 4) Pp[100 + lane] = 0ULL;
    __syncthreads();
    for (int r = lane; r < DB_H; r += 64) {
        const int bitpos = r * DB_W;
        const int q = bitpos >> 6, off = bitpos & 63;
        unsigned long long a, b;
        if (off) {
            a = (Pp[q] >> off) | (Pp[q + 1] << (64 - off));
            b = (Pp[q + 1] >> off) | (Pp[q + 2] << (64 - off));
        } else {
            a = Pp[q]; b = Pp[q + 1];
        }
        b &= 0xFFFFULL;
        unsigned long long ra = a, rb = b;
        #pragma unroll
        for (int s = 1; s <= 4; ++s) {
            ra |= a << s;
            rb |= (b << s) | (a >> (64 - s));
        }
        rb &= 0xFFFFULL;
        ro[r * 3 + 0] = (unsigned int)ra;
        ro[r * 3 + 1] = (unsigned int)(ra >> 32);
        ro[r * 3 + 2] = (unsigned int)rb;
    }
    __syncthreads();
    unsigned int* bmp = BM[wid];
    for (int i = lane; i < DB_H; i += 64) {
        const int lo = (i >= 4) ? i - 4 : 0;
        unsigned int c0 = 0, c1 = 0, c2 = 0;
        for (int ii = lo; ii <= i; ++ii) {
            c0 |= ro[ii * 3 + 0];
            c1 |= ro[ii * 3 + 1];
            c2 |= ro[ii * 3 + 2];
        }
        bmp[i * 3 + 0] = c0; bmp[i * 3 + 1] = c1; bmp[i * 3 + 2] = c2;
    }
    __syncthreads();
    const float* xp = x + plane * DB_PLANE;
    float* op = out + plane * DB_PLANE;
    for (int e = lane; e < DB_PLANE; e += 64) {
        int i = e / DB_W, j = e - i * DB_W;
        unsigned int wb = bmp[i * 3 + (j >> 5)] >> (j & 31);
        op[e] = (wb & 1u) ? 0.0f : xp[e] * scale;
    }
}

extern "C" void kernel_launch(void* const* d_in, const int* in_sizes, int n_in,
                              void* d_out, int out_size, void* d_ws, size_t ws_size,
                              hipStream_t stream) {
    const float* x = (const float*)d_in[0];
    const int* mask = (const int*)d_in[1];
    float* out = (float*)d_out;

    unsigned int* counts = (unsigned int*)d_ws;
    unsigned int* bits = (unsigned int*)((char*)d_ws + DB_CNT_BYTES);
    const size_t bits_bytes = (size_t)DB_NPLANES * DB_PLANE_WORDS * 4;
    const bool use_bits = ws_size >= DB_CNT_BYTES + bits_bytes;

    if (use_bits) {
        db_mask_kernel<<<DB_NPLANES / WPB, 256, 0, stream>>>(mask, bits, counts);
        db_apply_bits<<<2048, 256, 0, stream>>>(
            (const float4*)x, bits, counts, (float4*)out);
    } else {
        db_count_kernel<<<DB_NPLANES / WPB, 256, 0, stream>>>(mask, counts);
        db_apply_recompute<<<DB_NPLANES / WPB, 256, 0, stream>>>(
            x, mask, counts, out);
    }
}

// Round 7
// 65.110 us; speedup vs baseline: 5.0938x; 1.0154x over previous
//
#include <hip/hip_runtime.h>

// DropBlock, N=64 C=64 H=80 W=80, block_size=5 (top/left-clipped window max).
// Bitboard formulation: seed mask packed 1 bit/elem via __ballot; width-5
// window-OR via 128-bit shifts (row pass) + 5-row OR (col pass).
// R7: mask kernel at 2 waves/plane (8192 waves = 32/CU) with v[10] load
// bursts and outer loop NOT unrolled (VGPR ~40; R6's full unroll likely
// ballooned VGPRs / halved occupancy). Apply gains predicated x-load skip
// for fully-blocked float4s. No atomics, no memset in graph (R4/R5 lessons).
#define DB_H 80
#define DB_W 80
#define DB_PLANE (DB_H * DB_W)               // 6400
#define DB_NPLANES 4096                      // N*C
#define DB_ROW_WORDS 3                       // 96-bit padded row of block mask
#define DB_PLANE_WORDS (DB_H * DB_ROW_WORDS) // 240
#define DB_TOTAL (DB_PLANE * DB_NPLANES)     // 26214400
#define DB_COUNT_F 26214400.0f               // 25 * 2^20 — exact in f32
#define DB_CNT_BYTES (DB_NPLANES * 4)        // 16384
#define PPBLK 2                              // planes per block (2 waves each)
#define WPB 4                                // fallback kernels only

// Kernel 1: per-plane bitboard window-OR + zero count + packed mask store.
// Block = 4 waves = 2 planes; each wave owns one half (50 qwords / 40 rows).
__global__ __launch_bounds__(256) void db_mask_kernel(
    const int* __restrict__ mask,
    unsigned int* __restrict__ bits,
    unsigned int* __restrict__ counts)
{
    __shared__ unsigned long long P[PPBLK][104];        // packed seed bits
    __shared__ unsigned int RO[PPBLK][DB_PLANE_WORDS];  // row-OR, 3 words/row
    __shared__ unsigned int ZP[PPBLK][2];               // zero partials
    const int t = threadIdx.x;
    const int wid = t >> 6, lane = t & 63;
    const int pib = wid >> 1, half = wid & 1;
    const int plane = blockIdx.x * PPBLK + pib;
    const int* mp = mask + plane * DB_PLANE;
    unsigned long long* Pp = P[pib];
    unsigned int* ro = RO[pib];

    // Phase 1: this wave packs qword groups [half*50, half*50+50) in bursts
    // of 10 (10 loads in flight, then 10 ballots). Outer loop NOT unrolled.
    #pragma unroll 1
    for (int c = 0; c < 5; ++c) {
        int v[10];
        const int base = half * 50 + c * 10;
        #pragma unroll
        for (int k = 0; k < 10; ++k) v[k] = mp[(base + k) * 64 + lane];
        #pragma unroll
        for (int k = 0; k < 10; ++k) {
            unsigned long long bal = __ballot(v[k] & 1);
            if (lane == 0) Pp[base + k] = bal;
        }
    }
    if (t < 2 * 4) P[t >> 2][100 + (t & 3)] = 0ULL;   // zero pad both planes
    __syncthreads();

    // Phase 2: row sliding-OR (width 5, left-clipped) for rows
    // [half*40, half*40+40). Row = 80 bits as 128-bit (b:a).
    if (lane < 40) {
        const int r = half * 40 + lane;
        const int bitpos = r * DB_W;
        const int q = bitpos >> 6, off = bitpos & 63;
        unsigned long long a, b;
        if (off) {
            a = (Pp[q] >> off) | (Pp[q + 1] << (64 - off));
            b = (Pp[q + 1] >> off) | (Pp[q + 2] << (64 - off));
        } else {
            a = Pp[q]; b = Pp[q + 1];
        }
        b &= 0xFFFFULL;
        unsigned long long ra = a, rb = b;
        #pragma unroll
        for (int s = 1; s <= 4; ++s) {
            ra |= a << s;
            rb |= (b << s) | (a >> (64 - s));
        }
        rb &= 0xFFFFULL;
        ro[r * 3 + 0] = (unsigned int)ra;
        ro[r * 3 + 1] = (unsigned int)(ra >> 32);
        ro[r * 3 + 2] = (unsigned int)rb;
    }
    __syncthreads();

    // Phase 3: col OR over rows i-4..i (top clip), count zeros, store bits.
    unsigned int zeros = 0;
    if (lane < 40) {
        const int i = half * 40 + lane;
        const int lo = (i >= 4) ? i - 4 : 0;
        unsigned int c0 = 0, c1 = 0, c2 = 0;
        for (int ii = lo; ii <= i; ++ii) {
            c0 |= ro[ii * 3 + 0];
            c1 |= ro[ii * 3 + 1];
            c2 |= ro[ii * 3 + 2];
        }
        zeros = 80u - __popc(c0) - __popc(c1) - __popc(c2);
        unsigned int* bp = bits + plane * DB_PLANE_WORDS + i * 3;
        bp[0] = c0; bp[1] = c1; bp[2] = c2;
    }
    for (int off = 32; off > 0; off >>= 1)
        zeros += (unsigned int)__shfl_down((int)zeros, off, 64);
    if (lane == 0) ZP[pib][half] = zeros;
    __syncthreads();
    if (lane == 0 && half == 0)
        counts[plane] = ZP[pib][0] + ZP[pib][1];   // plain store, no init
}

// Kernel 2: out = blocked ? 0 : x * (countM / count_zeros), float4 stream.
// Prologue: block-local sum of the 4096 per-plane counts (L3-hit, 16KB).
// Predicated x-load: fully-blocked quads (nib==0xF) skip the 16B read.
__global__ __launch_bounds__(256) void db_apply_bits(
    const float4* __restrict__ x,
    const unsigned int* __restrict__ bits,
    const unsigned int* __restrict__ counts,
    float4* __restrict__ out)
{
    __shared__ float s_scale;
    __shared__ unsigned int s_part[4];
    {
        const uint4* cp = (const uint4*)counts;   // 1024 uint4
        unsigned int c = 0;
        #pragma unroll
        for (int k = 0; k < 4; ++k) {
            uint4 v = cp[k * 256 + threadIdx.x];
            c += v.x + v.y + v.z + v.w;
        }
        for (int off = 32; off > 0; off >>= 1)
            c += (unsigned int)__shfl_down((int)c, off, 64);
        if ((threadIdx.x & 63) == 0) s_part[threadIdx.x >> 6] = c;
        __syncthreads();
        if (threadIdx.x == 0)
            s_scale = DB_COUNT_F /
                      (float)(s_part[0] + s_part[1] + s_part[2] + s_part[3]);
        __syncthreads();
    }
    const float scale = s_scale;
    const int NG = DB_TOTAL / 4;
    const int stride = gridDim.x * blockDim.x;
    #pragma unroll 2
    for (int g = blockIdx.x * blockDim.x + threadIdx.x; g < NG; g += stride) {
        int e = g * 4;
        int plane = e / DB_PLANE;
        int ep = e - plane * DB_PLANE;
        int i = ep / DB_W;
        int j = ep - i * DB_W;   // j % 4 == 0; 4 bits never cross a word
        unsigned int nib =
            (bits[plane * DB_PLANE_WORDS + i * 3 + (j >> 5)] >> (j & 31)) & 0xFu;
        float4 v = make_float4(0.f, 0.f, 0.f, 0.f);
        if (nib != 0xFu) v = x[g];
        float4 o;
        o.x = (nib & 1u) ? 0.0f : v.x * scale;
        o.y = (nib & 2u) ? 0.0f : v.y * scale;
        o.z = (nib & 4u) ? 0.0f : v.z * scale;
        o.w = (nib & 8u) ? 0.0f : v.w * scale;
        out[g] = o;
    }
}

// ---- Fallback path (ws too small for bits) — structure from R6. ----
__global__ __launch_bounds__(256) void db_count_kernel(
    const int* __restrict__ mask,
    unsigned int* __restrict__ counts)
{
    __shared__ unsigned long long P[WPB][104];
    __shared__ unsigned int RO[WPB][DB_PLANE_WORDS];
    const int wid = threadIdx.x >> 6, lane = threadIdx.x & 63;
    const int plane = blockIdx.x * WPB + wid;
    const int* mp = mask + plane * DB_PLANE;
    unsigned long long* Pp = P[wid];
    unsigned int* ro = RO[wid];
    #pragma unroll 1
    for (int c = 0; c < 10; ++c) {
        int v[10];
        #pragma unroll
        for (int k = 0; k < 10; ++k) v[k] = mp[(c * 10 + k) * 64 + lane];
        #pragma unroll
        for (int k = 0; k < 10; ++k) {
            unsigned long long bal = __ballot(v[k] & 1);
            if (lane == 0) Pp[c * 10 + k] = bal;
        }
    }
    if (lane < 4) Pp[100 + lane] = 0ULL;
    __syncthreads();
    for (int r = lane; r < DB_H; r += 64) {
        const int bitpos = r * DB_W;
        const int q = bitpos >> 6, off = bitpos & 63;
        unsigned long long a, b;
        if (off) {
            a = (Pp[q] >> off) | (Pp[q + 1] << (64 - off));
            b = (Pp[q + 1] >> off) | (Pp[q + 2] << (64 - off));
        } else {
            a = Pp[q]; b = Pp[q + 1];
        }
        b &= 0xFFFFULL;
        unsigned long long ra = a, rb = b;
        #pragma unroll
        for (int s = 1; s <= 4; ++s) {
            ra |= a << s;
            rb |= (b << s) | (a >> (64 - s));
        }
        rb &= 0xFFFFULL;
        ro[r * 3 + 0] = (unsigned int)ra;
        ro[r * 3 + 1] = (unsigned int)(ra >> 32);
        ro[r * 3 + 2] = (unsigned int)rb;
    }
    __syncthreads();
    unsigned int zeros = 0;
    for (int i = lane; i < DB_H; i += 64) {
        const int lo = (i >= 4) ? i - 4 : 0;
        unsigned int c0 = 0, c1 = 0, c2 = 0;
        for (int ii = lo; ii <= i; ++ii) {
            c0 |= ro[ii * 3 + 0];
            c1 |= ro[ii * 3 + 1];
            c2 |= ro[ii * 3 + 2];
        }
        zeros += 80u - __popc(c0) - __popc(c1) - __popc(c2);
    }
    for (int off = 32; off > 0; off >>= 1)
        zeros += (unsigned int)__shfl_down((int)zeros, off, 64);
    if (lane == 0) counts[plane] = zeros;
}

__global__ __launch_bounds__(256) void db_apply_recompute(
    const float* __restrict__ x,
    const int* __restrict__ mask,
    const unsigned int* __restrict__ counts,
    float* __restrict__ out)
{
    __shared__ unsigned long long P[WPB][104];
    __shared__ unsigned int RO[WPB][DB_PLANE_WORDS];
    __shared__ unsigned int BM[WPB][DB_PLANE_WORDS];
    __shared__ float s_scale;
    __shared__ unsigned int s_part[4];
    {
        const uint4* cp = (const uint4*)counts;
        unsigned int c = 0;
        #pragma unroll
        for (int k = 0; k < 4; ++k) {
            uint4 v = cp[k * 256 + threadIdx.x];
            c += v.x + v.y + v.z + v.w;
        }
        for (int off = 32; off > 0; off >>= 1)
            c += (unsigned int)__shfl_down((int)c, off, 64);
        if ((threadIdx.x & 63) == 0) s_part[threadIdx.x >> 6] = c;
        __syncthreads();
        if (threadIdx.x == 0)
            s_scale = DB_COUNT_F /
                      (float)(s_part[0] + s_part[1] + s_part[2] + s_part[3]);
        __syncthreads();
    }
    const float scale = s_scale;
    const int wid = threadIdx.x >> 6, lane = threadIdx.x & 63;
    const int plane = blockIdx.x * WPB + wid;
    const int* mp = mask + plane * DB_PLANE;
    unsigned long long* Pp = P[wid];
    unsigned int* ro = RO[wid];
    #pragma unroll 1
    for (int c = 0; c < 10; ++c) {
        int v[10];
        #pragma unroll
        for (int k = 0; k < 10; ++k) v[k] = mp[(c * 10 + k) * 64 + lane];
        #pragma unroll
        for (int k = 0; k < 10; ++k) {
            unsigned long long bal = __ballot(v[k] & 1);
            if (lane == 0) Pp[c * 10 + k] = bal;
        }
    }
    if (lane < 4) Pp[100 + lane] = 0ULL;
    __syncthreads();
    for (int r = lane; r < DB_H; r += 64) {
        const int bitpos = r * DB_W;
        const int q = bitpos >> 6, off = bitpos & 63;
        unsigned long long a, b;
        if (off) {
            a = (Pp[q] >> off) | (Pp[q + 1] << (64 - off));
            b = (Pp[q + 1] >> off) | (Pp[q + 2] << (64 - off));
        } else {
            a = Pp[q]; b = Pp[q + 1];
        }
        b &= 0xFFFFULL;
        unsigned long long ra = a, rb = b;
        #pragma unroll
        for (int s = 1; s <= 4; ++s) {
            ra |= a << s;
            rb |= (b << s) | (a >> (64 - s));
        }
        rb &= 0xFFFFULL;
        ro[r * 3 + 0] = (unsigned int)ra;
        ro[r * 3 + 1] = (unsigned int)(ra >> 32);
        ro[r * 3 + 2] = (unsigned int)rb;
    }
    __syncthreads();
    unsigned int* bmp = BM[wid];
    for (int i = lane; i < DB_H; i += 64) {
        const int lo = (i >= 4) ? i - 4 : 0;
        unsigned int c0 = 0, c1 = 0, c2 = 0;
        for (int ii = lo; ii <= i; ++ii) {
            c0 |= ro[ii * 3 + 0];
            c1 |= ro[ii * 3 + 1];
            c2 |= ro[ii * 3 + 2];
        }
        bmp[i * 3 + 0] = c0; bmp[i * 3 + 1] = c1; bmp[i * 3 + 2] = c2;
    }
    __syncthreads();
    const float* xp = x + plane * DB_PLANE;
    float* op = out + plane * DB_PLANE;
    for (int e = lane; e < DB_PLANE; e += 64) {
        int i = e / DB_W, j = e - i * DB_W;
        unsigned int wb = bmp[i * 3 + (j >> 5)] >> (j & 31);
        op[e] = (wb & 1u) ? 0.0f : xp[e] * scale;
    }
}

extern "C" void kernel_launch(void* const* d_in, const int* in_sizes, int n_in,
                              void* d_out, int out_size, void* d_ws, size_t ws_size,
                              hipStream_t stream) {
    const float* x = (const float*)d_in[0];
    const int* mask = (const int*)d_in[1];
    float* out = (float*)d_out;

    unsigned int* counts = (unsigned int*)d_ws;
    unsigned int* bits = (unsigned int*)((char*)d_ws + DB_CNT_BYTES);
    const size_t bits_bytes = (size_t)DB_NPLANES * DB_PLANE_WORDS * 4;
    const bool use_bits = ws_size >= DB_CNT_BYTES + bits_bytes;

    if (use_bits) {
        db_mask_kernel<<<DB_NPLANES / PPBLK, 256, 0, stream>>>(mask, bits, counts);
        db_apply_bits<<<2048, 256, 0, stream>>>(
            (const float4*)x, bits, counts, (float4*)out);
    } else {
        db_count_kernel<<<DB_NPLANES / WPB, 256, 0, stream>>>(mask, counts);
        db_apply_recompute<<<DB_NPLANES / WPB, 256, 0, stream>>>(
            x, mask, counts, out);
    }
}